// Round 10
// baseline (1024.188 us; speedup 1.0000x reference)
//
#include <hip/hip_runtime.h>

#define HID    64
#define TSTEPS 256
#define BATCH  2048

typedef float v2f __attribute__((ext_vector_type(2)));

// tanh(x) = 1 - 2/(exp2(2*log2(e)*x) + 1); exact at saturation
__device__ __forceinline__ float fast_tanh(float x) {
    float e = __builtin_amdgcn_exp2f(x * 2.8853900817779268f);
    float r = __builtin_amdgcn_rcpf(e + 1.0f);
    return fmaf(-2.0f, r, 1.0f);
}

// ds_swizzle xor-exchange within 32-lane halves (BitMode: xor=M, and=0x1F)
template <int M>
__device__ __forceinline__ float swz(float v) {
    return __int_as_float(__builtin_amdgcn_ds_swizzle(
        __float_as_int(v), (M << 10) | 0x1F));
}

// DPP move. 0xB1 quad_perm=lane^1, 0x4E quad_perm=lane^2, 0x128 row_ror:8 (==lane^8)
template <int CTRL>
__device__ __forceinline__ float dppx(float x) {
    int xi = __float_as_int(x);
    return __int_as_float(__builtin_amdgcn_update_dpp(xi, xi, CTRL, 0xF, 0xF, false));
}

__device__ __forceinline__ float bperm(int addr, float v) {
    return __int_as_float(__builtin_amdgcn_ds_bpermute(addr, __float_as_int(v)));
}

// packed f32 FMA, all operands 64-bit pairs
__device__ __forceinline__ void pkfma(v2f& acc, v2f w, v2f hv) {
    asm("v_pk_fma_f32 %0, %1, %2, %0" : "+v"(acc) : "v"(w), "v"(hv));
}

// full 64-lane sum via DPP rotates + row broadcasts; uniform result (lane 63)
__device__ __forceinline__ float wave_sum(float v) {
    v += dppx<0x121>(v);                       // ror:1
    v += dppx<0x122>(v);                       // ror:2
    v += dppx<0x124>(v);                       // ror:4
    v += dppx<0x128>(v);                       // ror:8  -> 16-row totals
    v += __int_as_float(__builtin_amdgcn_update_dpp(
            0, __float_as_int(v), 0x142, 0xA, 0xF, false));   // bcast15
    v += __int_as_float(__builtin_amdgcn_update_dpp(
            0, __float_as_int(v), 0x143, 0xC, 0xF, false));   // bcast31
    return __int_as_float(__builtin_amdgcn_readlane(__float_as_int(v), 63));
}

__device__ __forceinline__ constexpr int rev3(int x) {   // 3-bit reversal
    return ((x & 1) << 2) | (x & 2) | ((x >> 2) & 1);
}

// 2 batch elements per wave: weights (shared across batch) amortized 2x,
// 1024 waves = exactly 1 wave/SIMD -> waves_per_eu(1,1) grants ~512 arch VGPRs.
__global__ __launch_bounds__(256) __attribute__((amdgpu_waves_per_eu(1, 1)))
void hnn_rk4_kernel(
        const float* __restrict__ tarr,
        const float* __restrict__ x0,
        const float* __restrict__ W1,
        const float* __restrict__ b1,
        const float* __restrict__ W2,
        const float* __restrict__ b2,
        const float* __restrict__ W3,
        float* __restrict__ out)
{
    const int lane = threadIdx.x & 63;
    const int wid  = threadIdx.x >> 6;
    const int w    = blockIdx.x * 4 + wid;     // wave id in [0,1024)
    const int bA   = w;
    const int bB   = w + 1024;

    // 8x8 lane grid (structure proven R8): lane (rr,cc) owns W2 rows 8rr..+7 x
    // cols 8cc..+7, hidden unit uo = 8rr+rev3(cc); ends holding u[vu].
    const int rr = lane >> 3, cc = lane & 7;
    const int pc = rev3(cc),  pr = rev3(rr);
    const int uo = 8 * rr + pc;
    const int vu = 8 * cc + pr;

    const float dt  = tarr[1] - tarr[0];
    const float hdt = 0.5f * dt;
    const float sdt = dt * (1.0f / 6.0f);

    const float w1a = W1[2 * uo + 0];
    const float w1b = W1[2 * uo + 1];
    const float b1i = b1[uo];
    const float b2i = b2[uo];
    const float w3i = W3[uo];
    const float w1va = W1[2 * vu + 0];
    const float w1vb = W1[2 * vu + 1];

    int ba[8], br[8];
#pragma unroll
    for (int t = 0; t < 8; ++t) {
        ba[t] = (8 * cc + rev3(t)) * 4;        // owner of h1[8cc+t]
        br[t] = (8 * rr + rev3(t)) * 4;        // owner of g2[8rr+t]
    }
    int a32 = (lane ^ 32) * 4;
    int ath = (8 * cc + rr) * 4;               // owner of h1[vu]

    // forward + backward weight pairs (R8 layout, proven)
    v2f wsF[8][4], wsB[8][4];
#pragma unroll
    for (int t = 0; t < 8; ++t) {
#pragma unroll
        for (int m = 0; m < 4; ++m) {
            v2f f;
            f.x = W2[(8 * rr + ((2 * m)     ^ pc)) * HID + 8 * cc + t];
            f.y = W2[(8 * rr + ((2 * m + 1) ^ pc)) * HID + 8 * cc + t];
            wsF[t][m] = f;
            v2f g;
            g.x = W2[(8 * rr + t) * HID + 8 * cc + ((2 * m)     ^ pr)];
            g.y = W2[(8 * rr + t) * HID + 8 * cc + ((2 * m + 1) ^ pr)];
            wsB[t][m] = g;
        }
    }
#pragma unroll
    for (int t = 0; t < 8; ++t)
#pragma unroll
        for (int m = 0; m < 4; ++m)
            asm("" : "+v"(wsF[t][m]), "+v"(wsB[t][m]));

    float qA = x0[2 * bA + 0], pA = x0[2 * bA + 1];
    float qB = x0[2 * bB + 0], pB = x0[2 * bB + 1];

    v2f* out2 = (v2f*)out;
    if (lane == 0) {
        v2f oA; oA.x = qA; oA.y = pA;  out2[bA] = oA;
        v2f oB; oB.x = qB; oB.y = pB;  out2[bB] = oB;
    }

    // dynamics for BOTH elements, interleaved: B's chains hide A's latencies.
    auto dyn2 = [&](float xqA, float xpA, float xqB, float xpB,
                    float& kqA, float& kpA, float& kqB, float& kpB) {
        const float h1A = fast_tanh(fmaf(w1a, xqA, fmaf(w1b, xpA, b1i)));
        const float h1B = fast_tanh(fmaf(w1a, xqB, fmaf(w1b, xpB, b1i)));

        float hbA[8], hbB[8];
#pragma unroll
        for (int t = 0; t < 8; ++t) {
            hbA[t] = bperm(ba[t], h1A);
            hbB[t] = bperm(ba[t], h1B);
        }
        const float h1vA = bperm(ath, h1A);
        const float h1vB = bperm(ath, h1B);

        v2f PA0 = {0.f,0.f}, PA1 = {0.f,0.f}, PA2 = {0.f,0.f}, PA3 = {0.f,0.f};
        v2f PB0 = {0.f,0.f}, PB1 = {0.f,0.f}, PB2 = {0.f,0.f}, PB3 = {0.f,0.f};
#pragma unroll
        for (int t = 0; t < 8; ++t) {
            v2f hvA; hvA.x = hbA[t]; hvA.y = hbA[t];
            v2f hvB; hvB.x = hbB[t]; hvB.y = hbB[t];
            pkfma(PA0, wsF[t][0], hvA);  pkfma(PB0, wsF[t][0], hvB);
            pkfma(PA1, wsF[t][1], hvA);  pkfma(PB1, wsF[t][1], hvB);
            pkfma(PA2, wsF[t][2], hvA);  pkfma(PB2, wsF[t][2], hvB);
            pkfma(PA3, wsF[t][3], hvA);  pkfma(PB3, wsF[t][3], hvB);
        }
        // uniform scatter-reduce over cc bits (proven R6/R8)
        PA0.x += dppx<0xB1>(PA2.x);  PA0.y += dppx<0xB1>(PA2.y);
        PB0.x += dppx<0xB1>(PB2.x);  PB0.y += dppx<0xB1>(PB2.y);
        PA1.x += dppx<0xB1>(PA3.x);  PA1.y += dppx<0xB1>(PA3.y);
        PB1.x += dppx<0xB1>(PB3.x);  PB1.y += dppx<0xB1>(PB3.y);
        PA0.x += dppx<0x4E>(PA1.x);  PA0.y += dppx<0x4E>(PA1.y);
        PB0.x += dppx<0x4E>(PB1.x);  PB0.y += dppx<0x4E>(PB1.y);
        const float pre2A = PA0.x + swz<4>(PA0.y) + b2i;
        const float pre2B = PB0.x + swz<4>(PB0.y) + b2i;

        const float h2A = fast_tanh(pre2A);
        const float h2B = fast_tanh(pre2B);
        const float g2A = w3i * fmaf(-h2A, h2A, 1.0f);
        const float g2B = w3i * fmaf(-h2B, h2B, 1.0f);

        float gbA[8], gbB[8];
#pragma unroll
        for (int o = 0; o < 8; ++o) {
            gbA[o] = bperm(br[o], g2A);
            gbB[o] = bperm(br[o], g2B);
        }

        v2f QA0 = {0.f,0.f}, QA1 = {0.f,0.f}, QA2 = {0.f,0.f}, QA3 = {0.f,0.f};
        v2f QB0 = {0.f,0.f}, QB1 = {0.f,0.f}, QB2 = {0.f,0.f}, QB3 = {0.f,0.f};
#pragma unroll
        for (int o = 0; o < 8; ++o) {
            v2f gvA; gvA.x = gbA[o]; gvA.y = gbA[o];
            v2f gvB; gvB.x = gbB[o]; gvB.y = gbB[o];
            pkfma(QA0, wsB[o][0], gvA);  pkfma(QB0, wsB[o][0], gvB);
            pkfma(QA1, wsB[o][1], gvA);  pkfma(QB1, wsB[o][1], gvB);
            pkfma(QA2, wsB[o][2], gvA);  pkfma(QB2, wsB[o][2], gvB);
            pkfma(QA3, wsB[o][3], gvA);  pkfma(QB3, wsB[o][3], gvB);
        }
        // uniform scatter-reduce over rr bits (lane^8, ^16, ^32)
        QA0.x += dppx<0x128>(QA2.x);  QA0.y += dppx<0x128>(QA2.y);
        QB0.x += dppx<0x128>(QB2.x);  QB0.y += dppx<0x128>(QB2.y);
        QA1.x += dppx<0x128>(QA3.x);  QA1.y += dppx<0x128>(QA3.y);
        QB1.x += dppx<0x128>(QB3.x);  QB1.y += dppx<0x128>(QB3.y);
        QA0.x += swz<16>(QA1.x);      QA0.y += swz<16>(QA1.y);
        QB0.x += swz<16>(QB1.x);      QB0.y += swz<16>(QB1.y);
        const float uvA = QA0.x + bperm(a32, QA0.y);   // = u[vu] for A
        const float uvB = QB0.x + bperm(a32, QB0.y);   // = u[vu] for B

        const float g1vA = uvA * fmaf(-h1vA, h1vA, 1.0f);
        const float g1vB = uvB * fmaf(-h1vB, h1vB, 1.0f);

        kqA =  wave_sum(g1vA * w1vb);
        kpA = -wave_sum(g1vA * w1va);
        kqB =  wave_sum(g1vB * w1vb);
        kpB = -wave_sum(g1vB * w1va);
    };

#pragma unroll 1
    for (int s = 0; s < TSTEPS - 1; ++s) {
        float kq1A,kp1A,kq2A,kp2A,kq3A,kp3A,kq4A,kp4A;
        float kq1B,kp1B,kq2B,kp2B,kq3B,kp3B,kq4B,kp4B;
        dyn2(qA, pA, qB, pB, kq1A, kp1A, kq1B, kp1B);
        dyn2(fmaf(hdt, kq1A, qA), fmaf(hdt, kp1A, pA),
             fmaf(hdt, kq1B, qB), fmaf(hdt, kp1B, pB), kq2A, kp2A, kq2B, kp2B);
        dyn2(fmaf(hdt, kq2A, qA), fmaf(hdt, kp2A, pA),
             fmaf(hdt, kq2B, qB), fmaf(hdt, kp2B, pB), kq3A, kp3A, kq3B, kp3B);
        dyn2(fmaf(dt,  kq3A, qA), fmaf(dt,  kp3A, pA),
             fmaf(dt,  kq3B, qB), fmaf(dt,  kp3B, pB), kq4A, kp4A, kq4B, kp4B);
        qA = fmaf(sdt, (kq1A + kq4A) + 2.0f * (kq2A + kq3A), qA);
        pA = fmaf(sdt, (kp1A + kp4A) + 2.0f * (kp2A + kp3A), pA);
        qB = fmaf(sdt, (kq1B + kq4B) + 2.0f * (kq2B + kq3B), qB);
        pB = fmaf(sdt, (kp1B + kp4B) + 2.0f * (kp2B + kp3B), pB);
        if (lane == 0) {
            v2f oA; oA.x = qA; oA.y = pA;
            v2f oB; oB.x = qB; oB.y = pB;
            out2[(s + 1) * BATCH + bA] = oA;
            out2[(s + 1) * BATCH + bB] = oB;
        }
    }
}

extern "C" void kernel_launch(void* const* d_in, const int* in_sizes, int n_in,
                              void* d_out, int out_size, void* d_ws, size_t ws_size,
                              hipStream_t stream) {
    const float* t  = (const float*)d_in[0];
    const float* x0 = (const float*)d_in[1];
    const float* W1 = (const float*)d_in[2];
    const float* b1 = (const float*)d_in[3];
    const float* W2 = (const float*)d_in[4];
    const float* b2 = (const float*)d_in[5];
    const float* W3 = (const float*)d_in[6];
    // d_in[7] = b3: additive constant in H, cancels in dH/dx — unused.

    // 1024 waves (2 elements each), 4 waves/block -> 256 blocks (one per CU)
    hnn_rk4_kernel<<<dim3(BATCH / 8), dim3(256), 0, stream>>>(
        t, x0, W1, b1, W2, b2, W3, (float*)d_out);
}

// Round 12
// 687.185 us; speedup vs baseline: 1.4904x; 1.4904x over previous
//
#include <hip/hip_runtime.h>

#define HID    64
#define TSTEPS 256
#define BATCH  2048

typedef float v2f __attribute__((ext_vector_type(2)));
typedef float v4f __attribute__((ext_vector_type(4)));

// tanh(x) = 1 - 2/(exp2(2*log2(e)*x) + 1); exact at saturation
__device__ __forceinline__ float fast_tanh(float x) {
    float e = __builtin_amdgcn_exp2f(x * 2.8853900817779268f);
    float r = __builtin_amdgcn_rcpf(e + 1.0f);
    return fmaf(-2.0f, r, 1.0f);
}

// ds_swizzle xor-exchange within 32-lane halves (BitMode: xor=M, and=0x1F)
template <int M>
__device__ __forceinline__ float swz(float v) {
    return __int_as_float(__builtin_amdgcn_ds_swizzle(
        __float_as_int(v), (M << 10) | 0x1F));
}

// DPP move. 0xB1 quad_perm=lane^1, 0x4E quad_perm=lane^2, 0x128 row_ror:8 (==lane^8)
template <int CTRL>
__device__ __forceinline__ float dppx(float x) {
    int xi = __float_as_int(x);
    return __int_as_float(__builtin_amdgcn_update_dpp(xi, xi, CTRL, 0xF, 0xF, false));
}

__device__ __forceinline__ float bperm(int addr, float v) {
    return __int_as_float(__builtin_amdgcn_ds_bpermute(addr, __float_as_int(v)));
}

// packed f32 FMA; op_sel variants broadcast the lo/hi half of the 64-bit h-pair
// to both product halves (all operands are legal 64-bit pairs — R7 errata)
__device__ __forceinline__ void pkfma_lo(v2f& acc, v2f w, v2f h) {
    asm("v_pk_fma_f32 %0, %1, %2, %0 op_sel_hi:[1,0,1]"
        : "+v"(acc) : "v"(w), "v"(h));
}
__device__ __forceinline__ void pkfma_hi(v2f& acc, v2f w, v2f h) {
    asm("v_pk_fma_f32 %0, %1, %2, %0 op_sel:[0,1,0] op_sel_hi:[1,1,1]"
        : "+v"(acc) : "v"(w), "v"(h));
}

// full 64-lane sum via DPP rotates + row broadcasts; uniform result (lane 63)
__device__ __forceinline__ float wave_sum(float v) {
    v += dppx<0x121>(v);                       // ror:1
    v += dppx<0x122>(v);                       // ror:2
    v += dppx<0x124>(v);                       // ror:4
    v += dppx<0x128>(v);                       // ror:8  -> 16-row totals
    v += __int_as_float(__builtin_amdgcn_update_dpp(
            0, __float_as_int(v), 0x142, 0xA, 0xF, false));   // bcast15
    v += __int_as_float(__builtin_amdgcn_update_dpp(
            0, __float_as_int(v), 0x143, 0xC, 0xF, false));   // bcast31
    return __int_as_float(__builtin_amdgcn_readlane(__float_as_int(v), 63));
}

__device__ __forceinline__ constexpr int rev3(int x) {   // 3-bit reversal
    return ((x & 1) << 2) | (x & 2) | ((x >> 2) & 1);
}

__global__ __launch_bounds__(256) __attribute__((amdgpu_waves_per_eu(2, 2)))
void hnn_rk4_kernel(
        const float* __restrict__ tarr,
        const float* __restrict__ x0,
        const float* __restrict__ W1,
        const float* __restrict__ b1,
        const float* __restrict__ W2,
        const float* __restrict__ b2,
        const float* __restrict__ W3,
        float* __restrict__ out)
{
    const int lane = threadIdx.x & 63;
    const int wid  = threadIdx.x >> 6;
    const int b    = blockIdx.x * 4 + wid;     // one wave per batch element

    // per-wave 64-float broadcast buffer, indexed by UNIT number
    __shared__ alignas(16) float sbuf[4][64];
    float* sb = sbuf[wid];

    // 8x8 lane grid (proven R8): lane (rr,cc) owns W2 rows 8rr..+7 x cols 8cc..+7,
    // hidden unit uo = 8rr+rev3(cc); ends holding u[vu], vu = 8cc+rev3(rr).
    const int rr = lane >> 3, cc = lane & 7;
    const int pc = rev3(cc),  pr = rev3(rr);
    const int uo = 8 * rr + pc;
    const int vu = 8 * cc + pr;

    const float dt  = tarr[1] - tarr[0];
    const float hdt = 0.5f * dt;
    const float sdt = dt * (1.0f / 6.0f);

    const float w1a = W1[2 * uo + 0];
    const float w1b = W1[2 * uo + 1];
    const float b1i = b1[uo];
    const float b2i = b2[uo];
    const float w3i = W3[uo];
    const float w1va = W1[2 * vu + 0];
    const float w1vb = W1[2 * vu + 1];

    int a32 = (lane ^ 32) * 4;                 // xor32 exchange (backward tail)

    // weight pairs (R8 layout, proven)
    v2f wsF[8][4], wsB[8][4];
#pragma unroll
    for (int t = 0; t < 8; ++t) {
#pragma unroll
        for (int m = 0; m < 4; ++m) {
            v2f f;
            f.x = W2[(8 * rr + ((2 * m)     ^ pc)) * HID + 8 * cc + t];
            f.y = W2[(8 * rr + ((2 * m + 1) ^ pc)) * HID + 8 * cc + t];
            wsF[t][m] = f;
            v2f g;
            g.x = W2[(8 * rr + t) * HID + 8 * cc + ((2 * m)     ^ pr)];
            g.y = W2[(8 * rr + t) * HID + 8 * cc + ((2 * m + 1) ^ pr)];
            wsB[t][m] = g;
        }
    }
#pragma unroll
    for (int t = 0; t < 8; ++t)
#pragma unroll
        for (int m = 0; m < 4; ++m)
            asm("" : "+v"(wsF[t][m]), "+v"(wsB[t][m]));

    float q = x0[2 * b + 0];
    float p = x0[2 * b + 1];

    if (lane == 0) {
        out[2 * b + 0] = q;
        out[2 * b + 1] = p;
    }

    auto dynamics = [&](float xq, float xp, float& kq, float& kp) {
        // layer 1 (own unit)
        const float h1 = fast_tanh(fmaf(w1a, xq, fmaf(w1b, xp, b1i)));

        // ---- broadcast h1 via LDS: scatter-write by unit, contiguous b128 reads.
        // Same-wave DS ops are in-order -> no barrier needed (R2-proven pattern).
        sb[uo] = h1;
        const v4f r0 = *(const v4f*)(sb + 8 * cc);      // h1[8cc+0..3]
        const v4f r1 = *(const v4f*)(sb + 8 * cc + 4);  // h1[8cc+4..7]
        const float h1v = sb[vu];                       // h1 of held unit vu
        const v2f h01 = r0.xy, h23 = r0.zw, h45 = r1.xy, h67 = r1.zw;

        // ---- forward: pre2 = W2 h1 + b2 (t-th term uses h1[8cc+t]) ----
        v2f P0 = {0.f,0.f}, P1 = {0.f,0.f}, P2 = {0.f,0.f}, P3 = {0.f,0.f};
        pkfma_lo(P0, wsF[0][0], h01); pkfma_lo(P1, wsF[0][1], h01);
        pkfma_lo(P2, wsF[0][2], h01); pkfma_lo(P3, wsF[0][3], h01);
        pkfma_hi(P0, wsF[1][0], h01); pkfma_hi(P1, wsF[1][1], h01);
        pkfma_hi(P2, wsF[1][2], h01); pkfma_hi(P3, wsF[1][3], h01);
        pkfma_lo(P0, wsF[2][0], h23); pkfma_lo(P1, wsF[2][1], h23);
        pkfma_lo(P2, wsF[2][2], h23); pkfma_lo(P3, wsF[2][3], h23);
        pkfma_hi(P0, wsF[3][0], h23); pkfma_hi(P1, wsF[3][1], h23);
        pkfma_hi(P2, wsF[3][2], h23); pkfma_hi(P3, wsF[3][3], h23);
        pkfma_lo(P0, wsF[4][0], h45); pkfma_lo(P1, wsF[4][1], h45);
        pkfma_lo(P2, wsF[4][2], h45); pkfma_lo(P3, wsF[4][3], h45);
        pkfma_hi(P0, wsF[5][0], h45); pkfma_hi(P1, wsF[5][1], h45);
        pkfma_hi(P2, wsF[5][2], h45); pkfma_hi(P3, wsF[5][3], h45);
        pkfma_lo(P0, wsF[6][0], h67); pkfma_lo(P1, wsF[6][1], h67);
        pkfma_lo(P2, wsF[6][2], h67); pkfma_lo(P3, wsF[6][3], h67);
        pkfma_hi(P0, wsF[7][0], h67); pkfma_hi(P1, wsF[7][1], h67);
        pkfma_hi(P2, wsF[7][2], h67); pkfma_hi(P3, wsF[7][3], h67);

        // uniform scatter-reduce over cc bits (proven R6/R8)
        P0.x += dppx<0xB1>(P2.x);  P0.y += dppx<0xB1>(P2.y);
        P1.x += dppx<0xB1>(P3.x);  P1.y += dppx<0xB1>(P3.y);
        P0.x += dppx<0x4E>(P1.x);  P0.y += dppx<0x4E>(P1.y);
        const float pre2 = P0.x + swz<4>(P0.y) + b2i;

        const float h2 = fast_tanh(pre2);
        const float g2 = w3i * fmaf(-h2, h2, 1.0f);

        // ---- broadcast g2 via LDS (reads of h1 above are already done: in-order)
        sb[uo] = g2;
        const v4f s0 = *(const v4f*)(sb + 8 * rr);      // g2[8rr+0..3]
        const v4f s1 = *(const v4f*)(sb + 8 * rr + 4);  // g2[8rr+4..7]
        const v2f g01 = s0.xy, g23 = s0.zw, g45 = s1.xy, g67 = s1.zw;

        // ---- backward: u = W2^T g2 (o-th term uses g2[8rr+o]) ----
        v2f Q0 = {0.f,0.f}, Q1 = {0.f,0.f}, Q2 = {0.f,0.f}, Q3 = {0.f,0.f};
        pkfma_lo(Q0, wsB[0][0], g01); pkfma_lo(Q1, wsB[0][1], g01);
        pkfma_lo(Q2, wsB[0][2], g01); pkfma_lo(Q3, wsB[0][3], g01);
        pkfma_hi(Q0, wsB[1][0], g01); pkfma_hi(Q1, wsB[1][1], g01);
        pkfma_hi(Q2, wsB[1][2], g01); pkfma_hi(Q3, wsB[1][3], g01);
        pkfma_lo(Q0, wsB[2][0], g23); pkfma_lo(Q1, wsB[2][1], g23);
        pkfma_lo(Q2, wsB[2][2], g23); pkfma_lo(Q3, wsB[2][3], g23);
        pkfma_hi(Q0, wsB[3][0], g23); pkfma_hi(Q1, wsB[3][1], g23);
        pkfma_hi(Q2, wsB[3][2], g23); pkfma_hi(Q3, wsB[3][3], g23);
        pkfma_lo(Q0, wsB[4][0], g45); pkfma_lo(Q1, wsB[4][1], g45);
        pkfma_lo(Q2, wsB[4][2], g45); pkfma_lo(Q3, wsB[4][3], g45);
        pkfma_hi(Q0, wsB[5][0], g45); pkfma_hi(Q1, wsB[5][1], g45);
        pkfma_hi(Q2, wsB[5][2], g45); pkfma_hi(Q3, wsB[5][3], g45);
        pkfma_lo(Q0, wsB[6][0], g67); pkfma_lo(Q1, wsB[6][1], g67);
        pkfma_lo(Q2, wsB[6][2], g67); pkfma_lo(Q3, wsB[6][3], g67);
        pkfma_hi(Q0, wsB[7][0], g67); pkfma_hi(Q1, wsB[7][1], g67);
        pkfma_hi(Q2, wsB[7][2], g67); pkfma_hi(Q3, wsB[7][3], g67);

        // scatter-reduce over rr bits (R8-verbatim, proven)
        Q0.x += dppx<0x128>(Q2.x);  Q0.y += dppx<0x128>(Q2.y);
        Q1.x += dppx<0x128>(Q3.x);  Q1.y += dppx<0x128>(Q3.y);
        Q0.x += swz<16>(Q1.x);      Q0.y += swz<16>(Q1.y);
        const float uv = Q0.x + bperm(a32, Q0.y);     // = u[vu], stays here

        // dH/dx contribution of unit vu; wave_sum is landing-agnostic
        const float g1v = uv * fmaf(-h1v, h1v, 1.0f);

        kq =  wave_sum(g1v * w1vb);   //  dH/dp
        kp = -wave_sum(g1v * w1va);   // -dH/dq
    };

#pragma unroll 1
    for (int s = 0; s < TSTEPS - 1; ++s) {
        float kq1, kp1, kq2, kp2, kq3, kp3, kq4, kp4;
        dynamics(q, p, kq1, kp1);
        dynamics(fmaf(hdt, kq1, q), fmaf(hdt, kp1, p), kq2, kp2);
        dynamics(fmaf(hdt, kq2, q), fmaf(hdt, kp2, p), kq3, kp3);
        dynamics(fmaf(dt,  kq3, q), fmaf(dt,  kp3, p), kq4, kp4);
        q = fmaf(sdt, (kq1 + kq4) + 2.0f * (kq2 + kq3), q);
        p = fmaf(sdt, (kp1 + kp4) + 2.0f * (kp2 + kp3), p);
        if (lane == 0) {
            out[(s + 1) * (BATCH * 2) + 2 * b + 0] = q;
            out[(s + 1) * (BATCH * 2) + 2 * b + 1] = p;
        }
    }
}

extern "C" void kernel_launch(void* const* d_in, const int* in_sizes, int n_in,
                              void* d_out, int out_size, void* d_ws, size_t ws_size,
                              hipStream_t stream) {
    const float* t  = (const float*)d_in[0];
    const float* x0 = (const float*)d_in[1];
    const float* W1 = (const float*)d_in[2];
    const float* b1 = (const float*)d_in[3];
    const float* W2 = (const float*)d_in[4];
    const float* b2 = (const float*)d_in[5];
    const float* W3 = (const float*)d_in[6];
    // d_in[7] = b3: additive constant in H, cancels in dH/dx — unused.

    hnn_rk4_kernel<<<dim3(BATCH / 4), dim3(256), 0, stream>>>(
        t, x0, W1, b1, W2, b2, W3, (float*)d_out);
}